// Round 13
// baseline (39.769 us; speedup 1.0000x reference)
//
#include <hip/hip_runtime.h>

// SoftHistLoss: x,y [16,3,512,512] f32 -> scalar f32
// R13: SUB-BIN INTEGER HISTOGRAM. Hot loop per pixel is only
//   j = trunc(v*2560);  ds_add_u32(&hist[(j<<1)|col], 1)     (~4 issue slots)
// (R8/R12 analysis: old kernel was VALU-issue-bound at ~15 ops/px = 69% busy;
// sigmoid math must leave the per-pixel path entirely.)
// Epilogue: sub-bin j = k*256 + f, f = j&255. Thread t owns f=t, and its 10
// rows j = t + 256r have exactly one row per bin r. Weights (mid-point rule):
//   wa = sigma(15*(t+.5)/256), wb = sigma(15*(t+.5)/256 - 15)   [full f32]
// Per-plane sums A[r]=sum wa*cnt, B[r]=sum wb*cnt, C[r]=sum cnt; reduce in
// fixed shuffle order (deterministic), round *64 to u32 once per block,
// accumulate via global integer atomics. hist_i = A-B + B[i-1] + C[i+1]-A[i+1].
// Lessons: no FP atomics on LDS (R2); no dependent LDS reads in hot loop (R9);
// no cold-epilogue fusion into a separate hot kernel's regalloc... epilogue
// here is tiny and integer-based; hot loop needs almost no registers anyway.

static constexpr int PLANES   = 48;               // 16*3 per image
static constexpr int PLANE_PX = 512 * 512;
static constexpr int SPP      = 16;               // sub-blocks per plane
static constexpr int THREADS  = 256;
static constexpr int CHUNK    = PLANE_PX / SPP;   // 16384 px/block, 64 px/thread
static constexpr int NBLK     = 96 * SPP;         // 1536 = 6 blocks/CU, one round
static constexpr int HWORDS   = 5124;             // (2560+2 pad rows) * 2 cols
static constexpr float E15    = 3269017.3724721107f;  // e^15

__global__ __launch_bounds__(THREADS, 6) void soft_hist_partial(
    const float* __restrict__ xin, const float* __restrict__ yin,
    unsigned* __restrict__ G /* [96][30] u32: {A,B,C}x10 bins, all x64 */)
{
  __shared__ unsigned hist[HWORDS];               // 20496 B
  __shared__ float fred[4][32];                   // cross-wave partials
  const int t = threadIdx.x;
  for (int i = t; i < HWORDS; i += THREADS) hist[i] = 0u;
  __syncthreads();

  const int blk   = blockIdx.x;
  const int plane = blk >> 4;                     // 0..95 (0..47 = x, 48..95 = y)
  const int sub   = blk & 15;
  const float* src = (plane < PLANES ? xin + (size_t)plane * PLANE_PX
                                     : yin + (size_t)(plane - PLANES) * PLANE_PX)
                   + (size_t)sub * CHUNK;
  const float4* src4 = (const float4*)src;
  const unsigned col = (unsigned)(t & 1);

  constexpr int ITERS = CHUNK / (THREADS * 4);    // 16
  float4 c0 = src4[t];
  float4 c1 = src4[THREADS + t];
  #pragma unroll 4
  for (int it = 0; it < ITERS; ++it) {
    float4 cur = c0;
    c0 = c1;
    if (it + 2 < ITERS) c1 = src4[(it + 2) * THREADS + t];
    float vv[4] = {cur.x, cur.y, cur.z, cur.w};
    #pragma unroll
    for (int jj = 0; jj < 4; ++jj) {
      unsigned j = (unsigned)(vv[jj] * 2560.0f);  // sub-bin; v in [0,1] -> <=2560 (pad)
      atomicAdd(&hist[(j << 1) | col], 1u);       // ds_add_u32, fire-and-forget
    }
  }
  __syncthreads();

  // ---- epilogue (cold): weights once per thread, full f32 ----
  float dm = ((float)t + 0.5f) * (1.0f / 256.0f); // mid-point of sub-bin, in d
  float ex = __expf(dm * -15.0f);                 // e^{-15d}
  float wa = 1.0f / (1.0f + ex);                  // sigma(15d)
  float wb = 1.0f / fmaf(E15, ex, 1.0f);          // sigma(15d-15)

  float pA[10], pB[10], pC[10];
  #pragma unroll
  for (int r = 0; r < 10; ++r) {
    const int idx = ((r << 8) + t) << 1;
    unsigned cn = hist[idx] + hist[idx | 1];
    float cf = (float)cn;
    pA[r] = wa * cf; pB[r] = wb * cf; pC[r] = cf;
  }
  #pragma unroll
  for (int off = 32; off >= 1; off >>= 1) {
    #pragma unroll
    for (int r = 0; r < 10; ++r) {
      pA[r] += __shfl_xor(pA[r], off, 64);
      pB[r] += __shfl_xor(pB[r], off, 64);
      pC[r] += __shfl_xor(pC[r], off, 64);
    }
  }
  const int lane = t & 63, w = t >> 6;
  if (lane == 0) {
    #pragma unroll
    for (int r = 0; r < 10; ++r) {
      fred[w][r * 3 + 0] = pA[r];
      fred[w][r * 3 + 1] = pB[r];
      fred[w][r * 3 + 2] = pC[r];
    }
  }
  __syncthreads();
  if (t < 30) {
    float s = fred[0][t] + fred[1][t] + fred[2][t] + fred[3][t];
    unsigned q = (unsigned)fmaf(s, 64.0f, 0.5f);  // x64 fixed-point, 1 round/block
    atomicAdd(&G[plane * 30 + t], q);             // deterministic integer atomic
  }
}

__global__ __launch_bounds__(512) void soft_hist_loss(
    const unsigned* __restrict__ G, float* __restrict__ out)
{
  __shared__ float wred[8];
  const int t = threadIdx.x;
  float val = 0.0f;
  if (t < 480) {
    const int pc = t / 10;        // (batch,channel) 0..47
    const int i  = t - pc * 10;   // bin
    const unsigned* gx = G + pc * 30;
    const unsigned* gy = G + (pc + PLANES) * 30;
    // (all entries x64; counts <= ~1.7e6 so f32-exact)
    // hist_i = A[i] - B[i] + B[i-1] + C[i+1] - A[i+1]
    float hx = (float)gx[3 * i] - (float)gx[3 * i + 1]
             + (i > 0 ? (float)gx[3 * (i - 1) + 1] : 0.0f)
             + (i < 9 ? (float)gx[3 * (i + 1) + 2] - (float)gx[3 * (i + 1)] : 0.0f);
    float hy = (float)gy[3 * i] - (float)gy[3 * i + 1]
             + (i > 0 ? (float)gy[3 * (i - 1) + 1] : 0.0f)
             + (i < 9 ? (float)gy[3 * (i + 1) + 2] - (float)gy[3 * (i + 1)] : 0.0f);
    val = fabsf(hx - hy);
  }
  #pragma unroll
  for (int off = 32; off >= 1; off >>= 1) val += __shfl_xor(val, off, 64);
  if ((t & 63) == 0) wred[t >> 6] = val;
  __syncthreads();
  if (t == 0) {
    float s = 0.0f;
    #pragma unroll
    for (int w = 0; w < 8; ++w) s += wred[w];
    // loss = sum * (1/64 fixedpoint) * (1/BINS) * (1/B) * 1e-4
    out[0] = s * 9.765625e-9f;
  }
}

extern "C" void kernel_launch(void* const* d_in, const int* in_sizes, int n_in,
                              void* d_out, int out_size, void* d_ws, size_t ws_size,
                              hipStream_t stream) {
  const float* x = (const float*)d_in[0];
  const float* y = (const float*)d_in[1];
  unsigned* G = (unsigned*)d_ws;               // 96*30*4 = 11520 B
  hipMemsetAsync(d_ws, 0, 96 * 30 * sizeof(unsigned), stream);
  soft_hist_partial<<<NBLK, THREADS, 0, stream>>>(x, y, G);
  soft_hist_loss<<<1, 512, 0, stream>>>(G, (float*)d_out);
}

// Round 14
// 29.832 us; speedup vs baseline: 1.3331x; 1.3331x over previous
//
#include <hip/hip_runtime.h>

// SoftHistLoss: x,y [16,3,512,512] f32 -> scalar f32
// R14: SUB-BIN HISTOGRAM with BANK-CONSTANT LDS atomics.
// Hot loop/px: j = trunc(v*160); ds_add_u32(&hist[(j<<5)|(t&31)], 1)
//   (~3 VALU + 1 ds; bank = t&31 -> always exactly 2 lanes/bank)
// R13 lesson: ds_add cost ~ 10cyc x max-lanes-per-bank; random sub-bin
// addresses gave ~7/bank = 70cyc/waveop = 44.6us. Lane-column layout
// restores the 2/bank floor while keeping the sub-bin algorithm's tiny
// VALU count (R8/R12: old 15-op/px sigmoid chain was the 69%-busy wall).
// Epilogue (cold, once/block): row r = bin*16+f, d_mid = (f+.5)/16,
//   wa = sigma(15 d_mid), wb = sigma(15 d_mid - 15)  [full f32]
// A[bin]=sum wa*cnt, B[bin]=sum wb*cnt, C[bin]=sum cnt; 16-lane shuffle
// reduce (fixed order), x64 fixed-point round once/block, integer global
// atomics (deterministic). hist_i = A[i]-B[i]+B[i-1]+C[i+1]-A[i+1].
// Mid-point bias is 2nd-order and cancels in hx-hy; residual ~1 count
// vs 1461-count threshold.
// Lessons: no FP atomics on LDS (R2); no dependent LDS reads in hot loop
// (R9); no fat epilogue fusion (R11); 1536 blocks = one occupancy round (R7).

static constexpr int PLANES   = 48;               // 16*3 per image
static constexpr int PLANE_PX = 512 * 512;
static constexpr int SPP      = 16;               // sub-blocks per plane
static constexpr int THREADS  = 256;
static constexpr int CHUNK    = PLANE_PX / SPP;   // 16384 px/block, 64 px/thread
static constexpr int NBLK     = 96 * SPP;         // 1536 = 6 blocks/CU, one round
static constexpr int ROWS     = 161;              // 160 sub-bins + pad (v==1.0)
static constexpr int HWORDS   = ROWS * 32;        // 5152 words = 20.6 KB
static constexpr float E15    = 3269017.3724721107f;  // e^15

__global__ __launch_bounds__(THREADS, 6) void soft_hist_partial(
    const float* __restrict__ xin, const float* __restrict__ yin,
    unsigned* __restrict__ G /* [96][30] u32: {A,B,C}x10 bins, all x64 */)
{
  __shared__ unsigned hist[HWORDS];
  __shared__ float fred[30];
  const int t = threadIdx.x;
  for (int i = t; i < HWORDS; i += THREADS) hist[i] = 0u;
  __syncthreads();

  const int blk   = blockIdx.x;
  const int plane = blk >> 4;                     // 0..95 (0..47 = x, 48..95 = y)
  const int sub   = blk & 15;
  const float* src = (plane < PLANES ? xin + (size_t)plane * PLANE_PX
                                     : yin + (size_t)(plane - PLANES) * PLANE_PX)
                   + (size_t)sub * CHUNK;
  const float4* src4 = (const float4*)src;
  unsigned* mycol = hist + (t & 31);              // bank = t&31, constant

  constexpr int ITERS = CHUNK / (THREADS * 4);    // 16
  float4 c0 = src4[t];
  float4 c1 = src4[THREADS + t];
  #pragma unroll 4
  for (int it = 0; it < ITERS; ++it) {
    float4 cur = c0;
    c0 = c1;
    if (it + 2 < ITERS) c1 = src4[(it + 2) * THREADS + t];
    float vv[4] = {cur.x, cur.y, cur.z, cur.w};
    #pragma unroll
    for (int jj = 0; jj < 4; ++jj) {
      unsigned j = (unsigned)(vv[jj] * 160.0f);   // sub-bin 0..160
      atomicAdd(&mycol[j << 5], 1u);              // ds_add_u32, 2 lanes/bank
    }
  }
  __syncthreads();

  // ---- cold epilogue: weights once, deterministic reduce ----
  if (t < 160) {
    const int f = t & 15;                         // sub-bin within bin
    float dm = ((float)f + 0.5f) * (1.0f / 16.0f);
    float ex = __expf(dm * -15.0f);               // e^{-15d}
    float wa = 1.0f / (1.0f + ex);                // sigma(15d)
    float wb = 1.0f / fmaf(E15, ex, 1.0f);        // sigma(15d-15)
    unsigned cn = 0;
    const unsigned* row = hist + (t << 5);
    #pragma unroll
    for (int c = 0; c < 32; ++c) cn += row[c];
    float cf = (float)cn;
    float pa = wa * cf, pb = wb * cf, pc = cf;
    // 16-lane group reduce (rows of one bin are 16 consecutive threads)
    #pragma unroll
    for (int off = 8; off >= 1; off >>= 1) {
      pa += __shfl_xor(pa, off, 16);
      pb += __shfl_xor(pb, off, 16);
      pc += __shfl_xor(pc, off, 16);
    }
    if (f == 0) {
      const int bin = t >> 4;
      fred[bin * 3 + 0] = pa;
      fred[bin * 3 + 1] = pb;
      fred[bin * 3 + 2] = pc;
    }
  }
  __syncthreads();
  if (t < 30) {
    unsigned q = (unsigned)fmaf(fred[t], 64.0f, 0.5f);  // x64, 1 round/block
    atomicAdd(&G[plane * 30 + t], q);             // deterministic int atomic
  }
}

__global__ __launch_bounds__(512) void soft_hist_loss(
    const unsigned* __restrict__ G, float* __restrict__ out)
{
  __shared__ float wred[8];
  const int t = threadIdx.x;
  float val = 0.0f;
  if (t < 480) {
    const int pc = t / 10;        // (batch,channel) 0..47
    const int i  = t - pc * 10;   // bin
    const unsigned* gx = G + pc * 30;
    const unsigned* gy = G + (pc + PLANES) * 30;
    // (entries x64; per-bin <= ~1.7M -> f32-exact)
    // hist_i = A[i] - B[i] + B[i-1] + C[i+1] - A[i+1]
    float hx = (float)gx[3 * i] - (float)gx[3 * i + 1]
             + (i > 0 ? (float)gx[3 * (i - 1) + 1] : 0.0f)
             + (i < 9 ? (float)gx[3 * (i + 1) + 2] - (float)gx[3 * (i + 1)] : 0.0f);
    float hy = (float)gy[3 * i] - (float)gy[3 * i + 1]
             + (i > 0 ? (float)gy[3 * (i - 1) + 1] : 0.0f)
             + (i < 9 ? (float)gy[3 * (i + 1) + 2] - (float)gy[3 * (i + 1)] : 0.0f);
    val = fabsf(hx - hy);
  }
  #pragma unroll
  for (int off = 32; off >= 1; off >>= 1) val += __shfl_xor(val, off, 64);
  if ((t & 63) == 0) wred[t >> 6] = val;
  __syncthreads();
  if (t == 0) {
    float s = 0.0f;
    #pragma unroll
    for (int w = 0; w < 8; ++w) s += wred[w];
    // loss = sum * (1/64) * (1/BINS) * (1/B) * 1e-4
    out[0] = s * 9.765625e-9f;
  }
}

extern "C" void kernel_launch(void* const* d_in, const int* in_sizes, int n_in,
                              void* d_out, int out_size, void* d_ws, size_t ws_size,
                              hipStream_t stream) {
  const float* x = (const float*)d_in[0];
  const float* y = (const float*)d_in[1];
  unsigned* G = (unsigned*)d_ws;               // 96*30*4 = 11520 B
  hipMemsetAsync(d_ws, 0, 96 * 30 * sizeof(unsigned), stream);
  soft_hist_partial<<<NBLK, THREADS, 0, stream>>>(x, y, G);
  soft_hist_loss<<<1, 512, 0, stream>>>(G, (float*)d_out);
}